// Round 16
// baseline (324.492 us; speedup 1.0000x reference)
//
#include <hip/hip_runtime.h>
#include <hip/hip_fp16.h>

#define BINS 10

typedef float f32x4 __attribute__((ext_vector_type(4)));  // native vec for nt-load

__device__ __forceinline__ unsigned pk_add_f16x2(unsigned a, unsigned b) {
    __half2 ha = __builtin_bit_cast(__half2, a);
    __half2 hb = __builtin_bit_cast(__half2, b);
    return __builtin_bit_cast(unsigned, __hadd2(ha, hb));   // v_pk_add_f16
}

// ===== ELEM MATH: byte-for-byte from R2/R8/R13/R15 (PASSED absmax 0.0). The
// z-form (R3-R7) fails on HW — banned. LDS atomics (R8/R14) and volatile RMW
// chains (R9) banned. Scatter: packed-f16 pair accumulators (R15, passed).
__device__ __forceinline__ void ghm_elem(float x, float tt,
                                         unsigned long long& pk,
                                         unsigned (&acc)[5]) {
    float t = __expf(-fabsf(x));                 // e^{-|x|}
    float u = 1.f + t;
    float r = __builtin_amdgcn_rcpf(u);          // ~1ulp approx, ample slack
    float sig = (x >= 0.f) ? r : t * r;          // sigmoid(x), all ranges
    float d = sig - tt;
    int idx = (int)(fabsf(d) * 10.f);            // trunc (validated R8/R10)
    idx = idx < 9 ? idx : 9;
    pk += 1ull << (6 * idx);                     // packed counts, 6b/bin
    float bce = fmaxf(x, 0.f) - x * tt + __logf(u);  // log1p(e^{-|x|}) = log(u)
    unsigned hv = (unsigned)__builtin_bit_cast(unsigned short, __float2half(bce));
    hv <<= ((idx & 1) << 4);                     // place in low/high half
    const int pair = idx >> 1;
#pragma unroll
    for (int p = 0; p < 5; ++p)                  // cmp + cndmask + pk_add
        acc[p] = pk_add_f16x2(acc[p], (pair == p) ? hv : 0u);
}

__global__ __launch_bounds__(256) void ghm_fused(
    const float* __restrict__ pred, const float* __restrict__ tgt,
    long long n, int nb,
    float* __restrict__ bsum, int* __restrict__ bcnt,
    unsigned int* __restrict__ done, float* __restrict__ out)
{
    __shared__ float rsum[4][BINS];
    __shared__ int   rcnt[4][BINS];

    const int tid  = threadIdx.x;
    const int lane = tid & 63;
    const int wave = tid >> 6;

    float s[BINS];
#pragma unroll
    for (int b = 0; b < BINS; ++b) s[b] = 0.f;
    unsigned acc[5];
#pragma unroll
    for (int p = 0; p < 5; ++p) acc[p] = 0u;
    unsigned long long pk = 0;
    int c[BINS];
#pragma unroll
    for (int b = 0; b < BINS; ++b) c[b] = 0;

    const long long n4 = n >> 2;
    const f32x4* p4 = (const f32x4*)pred;
    const f32x4* t4 = (const f32x4*)tgt;

    // Chunked contiguous partition + NT loads (R13, proven 51->40us).
    const long long qpb = (n4 + nb - 1) / nb;
    const long long q0  = (long long)blockIdx.x * qpb;
    const long long q1  = (q0 + qpb < n4) ? (q0 + qpb) : n4;

    int chunk = 0;
    for (long long i = q0 + tid; i < q1; i += 512) {   // unroll x2
        f32x4 pa = __builtin_nontemporal_load(&p4[i]);
        f32x4 ta = __builtin_nontemporal_load(&t4[i]);
        const long long j = i + 256;
        f32x4 pb, tb;
        const bool has2 = (j < q1);
        if (has2) {
            pb = __builtin_nontemporal_load(&p4[j]);
            tb = __builtin_nontemporal_load(&t4[j]);
        }
        ghm_elem(pa.x, ta.x, pk, acc);
        ghm_elem(pa.y, ta.y, pk, acc);
        ghm_elem(pa.z, ta.z, pk, acc);
        ghm_elem(pa.w, ta.w, pk, acc);
        if (has2) {
            ghm_elem(pb.x, tb.x, pk, acc);
            ghm_elem(pb.y, tb.y, pk, acc);
            ghm_elem(pb.z, tb.z, pk, acc);
            ghm_elem(pb.w, tb.w, pk, acc);
        }
        if (++chunk == 7) {   // 56 elems: 6-bit count fields <=63, f16 sums <=~320
            chunk = 0;
#pragma unroll
            for (int b = 0; b < BINS; ++b) c[b] += (int)((pk >> (6 * b)) & 63u);
            pk = 0;
#pragma unroll
            for (int p = 0; p < 5; ++p) {
                __half2 h = __builtin_bit_cast(__half2, acc[p]);
                s[2 * p]     += __half2float(__low2half(h));
                s[2 * p + 1] += __half2float(__high2half(h));
                acc[p] = 0u;
            }
        }
    }
    const long long tail0 = n4 << 2;     // n % 4 remainder: block 0
    if (blockIdx.x == 0 && (long long)tid < (n - tail0))
        ghm_elem(pred[tail0 + tid], tgt[tail0 + tid], pk, acc);
#pragma unroll
    for (int b = 0; b < BINS; ++b) c[b] += (int)((pk >> (6 * b)) & 63u);
#pragma unroll
    for (int p = 0; p < 5; ++p) {
        __half2 h = __builtin_bit_cast(__half2, acc[p]);
        s[2 * p]     += __half2float(__low2half(h));
        s[2 * p + 1] += __half2float(__high2half(h));
    }

    // block reduce: shuffle tree per bin, then cross-wave via LDS (validated)
#pragma unroll
    for (int b = 0; b < BINS; ++b) {
        float v = s[b];
        int   k = c[b];
        for (int off = 32; off; off >>= 1) {
            v += __shfl_down(v, off);
            k += __shfl_down(k, off);
        }
        if (lane == 0) { rsum[wave][b] = v; rcnt[wave][b] = k; }
    }
    __syncthreads();
    if (tid < BINS) {
        int b = tid;
        float v = rsum[0][b] + rsum[1][b] + rsum[2][b] + rsum[3][b];
        int   k = rcnt[0][b] + rcnt[1][b] + rcnt[2][b] + rcnt[3][b];
        bsum[(long long)b * nb + blockIdx.x] = v;   // bin-major partials
        bcnt[(long long)b * nb + blockIdx.x] = k;
    }

    // ---- last-block final reduce (removes pass2 launch, ~5-7us) ----
    // Release order (R4's bug was fence BEFORE sync): partial stores ->
    // __syncthreads (block-wide visible+ordered) -> __threadfence (device
    // release) -> ticket. `done` is memset to 0 in the captured graph, so
    // ticket nb-1 == genuinely last block.
    __syncthreads();
    __threadfence();
    __shared__ unsigned int is_last;
    if (tid == 0)
        is_last = (atomicAdd(done, 1u) == (unsigned)(nb - 1)) ? 1u : 0u;
    __syncthreads();
    if (!is_last) return;
    __threadfence();                 // acquire side

    __shared__ double    ssum[BINS];
    __shared__ long long scnt[BINS];
    for (int b = wave; b < BINS; b += 4) {   // 4 waves cover 10 bins
        double acc2 = 0.0; long long cc = 0;
        for (int i = lane; i < nb; i += 64) {
            // coherent loads: immune to cross-XCD L2 staleness (G16)
            float fv = __hip_atomic_load(&bsum[(long long)b * nb + i],
                                         __ATOMIC_RELAXED, __HIP_MEMORY_SCOPE_AGENT);
            int   iv = __hip_atomic_load(&bcnt[(long long)b * nb + i],
                                         __ATOMIC_RELAXED, __HIP_MEMORY_SCOPE_AGENT);
            acc2 += (double)fv;
            cc   += (long long)iv;
        }
        for (int off = 32; off; off >>= 1) {
            acc2 += __shfl_down(acc2, off);
            cc   += __shfl_down(cc, off);
        }
        if (lane == 0) { ssum[b] = acc2; scnt[b] = cc; }
    }
    __syncthreads();
    if (tid == 0) {
        int nn = 0;
#pragma unroll
        for (int b = 0; b < BINS; ++b) nn += (scnt[b] > 0) ? 1 : 0;
        double loss = 0.0;
        if (nn > 0) {
#pragma unroll
            for (int b = 0; b < BINS; ++b)
                if (scnt[b] > 0)
                    loss += ssum[b] / ((double)scnt[b] * (double)nn);
        }
        out[0] = (float)loss;
    }
}

extern "C" void kernel_launch(void* const* d_in, const int* in_sizes, int n_in,
                              void* d_out, int out_size, void* d_ws, size_t ws_size,
                              hipStream_t stream) {
    const float* pred = (const float*)d_in[0];
    const float* tgt  = (const float*)d_in[1];
    float* out = (float*)d_out;
    const long long n = (long long)in_sizes[0];

    int nb = 2048;
    const size_t per_block = (size_t)BINS * (sizeof(float) + sizeof(int)); // 80 B
    while (nb > 1 && (size_t)nb * per_block + sizeof(unsigned int) > ws_size)
        nb >>= 1;

    float*        bsum = (float*)d_ws;
    int*          bcnt = (int*)(bsum + (size_t)BINS * nb);
    unsigned int* done = (unsigned int*)(bcnt + (size_t)BINS * nb);

    // zero the ticket every call (captured into the graph -> every replay)
    hipMemsetAsync(done, 0, sizeof(unsigned int), stream);
    ghm_fused<<<nb, 256, 0, stream>>>(pred, tgt, n, nb, bsum, bcnt, done, out);
}

// Round 17
// 76.274 us; speedup vs baseline: 4.2543x; 4.2543x over previous
//
#include <hip/hip_runtime.h>
#include <hip/hip_fp16.h>

#define BINS 10

typedef float f32x4 __attribute__((ext_vector_type(4)));  // native vec for nt-load

__device__ __forceinline__ unsigned pk_add_f16x2(unsigned a, unsigned b) {
    __half2 ha = __builtin_bit_cast(__half2, a);
    __half2 hb = __builtin_bit_cast(__half2, b);
    return __builtin_bit_cast(unsigned, __hadd2(ha, hb));   // v_pk_add_f16
}

// ===== ELEM MATH: byte-for-byte from R2/R8/R13/R15 (PASSED absmax 0.0). The
// z-form (R3-R7) fails on HW — banned. LDS atomics (R8/R14) and volatile RMW
// chains (R9) banned. Scatter: packed-f16 pair accumulators (R15, passed).
__device__ __forceinline__ void ghm_elem(float x, float tt,
                                         unsigned long long& pk,
                                         unsigned (&acc)[5]) {
    float t = __expf(-fabsf(x));                 // e^{-|x|}
    float u = 1.f + t;
    float r = __builtin_amdgcn_rcpf(u);          // ~1ulp approx, ample slack
    float sig = (x >= 0.f) ? r : t * r;          // sigmoid(x), all ranges
    float d = sig - tt;
    int idx = (int)(fabsf(d) * 10.f);            // trunc (validated R8/R10)
    idx = idx < 9 ? idx : 9;
    pk += 1ull << (6 * idx);                     // packed counts, 6b/bin
    float bce = fmaxf(x, 0.f) - x * tt + __logf(u);  // log1p(e^{-|x|}) = log(u)
    unsigned hv = (unsigned)__builtin_bit_cast(unsigned short, __float2half(bce));
    hv <<= ((idx & 1) << 4);                     // place in low/high half
    const int pair = idx >> 1;
#pragma unroll
    for (int p = 0; p < 5; ++p)                  // cmp + cndmask + pk_add
        acc[p] = pk_add_f16x2(acc[p], (pair == p) ? hv : 0u);
}

// Fused single kernel, FENCE-FREE epilogue. R16's __threadfence() (agent
// release) emits buffer_wbl2 = full per-XCD L2 writeback; 2048 blocks x
// serialized wbl2 ~= 280us (VALUBusy 7.7% smoking gun). Instead: partials are
// written with relaxed AGENT atomic stores (sc0 sc1 write-through to the
// device-coherent point, no L2 writeback), drained with one s_waitcnt
// vmcnt(0), then the relaxed AGENT ticket. Winner reads with relaxed AGENT
// atomic loads (bypass possibly-stale L2). No wbl2 anywhere.
__global__ __launch_bounds__(256) void ghm_fused(
    const float* __restrict__ pred, const float* __restrict__ tgt,
    long long n, int nb,
    float* __restrict__ bsum, int* __restrict__ bcnt,
    unsigned int* __restrict__ done, float* __restrict__ out)
{
    __shared__ float rsum[4][BINS];
    __shared__ int   rcnt[4][BINS];

    const int tid  = threadIdx.x;
    const int lane = tid & 63;
    const int wave = tid >> 6;

    float s[BINS];
#pragma unroll
    for (int b = 0; b < BINS; ++b) s[b] = 0.f;
    unsigned acc[5];
#pragma unroll
    for (int p = 0; p < 5; ++p) acc[p] = 0u;
    unsigned long long pk = 0;
    int c[BINS];
#pragma unroll
    for (int b = 0; b < BINS; ++b) c[b] = 0;

    const long long n4 = n >> 2;
    const f32x4* p4 = (const f32x4*)pred;
    const f32x4* t4 = (const f32x4*)tgt;

    // Chunked contiguous partition + NT loads (R13, proven 51->40us).
    const long long qpb = (n4 + nb - 1) / nb;
    const long long q0  = (long long)blockIdx.x * qpb;
    const long long q1  = (q0 + qpb < n4) ? (q0 + qpb) : n4;

    int chunk = 0;
    for (long long i = q0 + tid; i < q1; i += 512) {   // unroll x2
        f32x4 pa = __builtin_nontemporal_load(&p4[i]);
        f32x4 ta = __builtin_nontemporal_load(&t4[i]);
        const long long j = i + 256;
        f32x4 pb, tb;
        const bool has2 = (j < q1);
        if (has2) {
            pb = __builtin_nontemporal_load(&p4[j]);
            tb = __builtin_nontemporal_load(&t4[j]);
        }
        ghm_elem(pa.x, ta.x, pk, acc);
        ghm_elem(pa.y, ta.y, pk, acc);
        ghm_elem(pa.z, ta.z, pk, acc);
        ghm_elem(pa.w, ta.w, pk, acc);
        if (has2) {
            ghm_elem(pb.x, tb.x, pk, acc);
            ghm_elem(pb.y, tb.y, pk, acc);
            ghm_elem(pb.z, tb.z, pk, acc);
            ghm_elem(pb.w, tb.w, pk, acc);
        }
        if (++chunk == 7) {   // 56 elems: 6-bit count fields <=63, f16 sums <=~320
            chunk = 0;
#pragma unroll
            for (int b = 0; b < BINS; ++b) c[b] += (int)((pk >> (6 * b)) & 63u);
            pk = 0;
#pragma unroll
            for (int p = 0; p < 5; ++p) {
                __half2 h = __builtin_bit_cast(__half2, acc[p]);
                s[2 * p]     += __half2float(__low2half(h));
                s[2 * p + 1] += __half2float(__high2half(h));
                acc[p] = 0u;
            }
        }
    }
    const long long tail0 = n4 << 2;     // n % 4 remainder: block 0
    if (blockIdx.x == 0 && (long long)tid < (n - tail0))
        ghm_elem(pred[tail0 + tid], tgt[tail0 + tid], pk, acc);
#pragma unroll
    for (int b = 0; b < BINS; ++b) c[b] += (int)((pk >> (6 * b)) & 63u);
#pragma unroll
    for (int p = 0; p < 5; ++p) {
        __half2 h = __builtin_bit_cast(__half2, acc[p]);
        s[2 * p]     += __half2float(__low2half(h));
        s[2 * p + 1] += __half2float(__high2half(h));
    }

    // block reduce: shuffle tree per bin, then cross-wave via LDS (validated)
#pragma unroll
    for (int b = 0; b < BINS; ++b) {
        float v = s[b];
        int   k = c[b];
        for (int off = 32; off; off >>= 1) {
            v += __shfl_down(v, off);
            k += __shfl_down(k, off);
        }
        if (lane == 0) { rsum[wave][b] = v; rcnt[wave][b] = k; }
    }
    __syncthreads();
    if (tid < BINS) {
        int b = tid;
        float v = rsum[0][b] + rsum[1][b] + rsum[2][b] + rsum[3][b];
        int   k = rcnt[0][b] + rcnt[1][b] + rcnt[2][b] + rcnt[3][b];
        // write-through device-coherent stores (sc0 sc1): no wbl2 needed
        __hip_atomic_store(&bsum[(long long)b * nb + blockIdx.x], v,
                           __ATOMIC_RELAXED, __HIP_MEMORY_SCOPE_AGENT);
        __hip_atomic_store(&bcnt[(long long)b * nb + blockIdx.x], k,
                           __ATOMIC_RELAXED, __HIP_MEMORY_SCOPE_AGENT);
    }
    // drain wave 0's sc-stores to the coherent point before the ticket
    if (wave == 0) asm volatile("s_waitcnt vmcnt(0)" ::: "memory");

    __shared__ unsigned int is_last;
    if (tid == 0)
        is_last = (__hip_atomic_fetch_add(done, 1u, __ATOMIC_RELAXED,
                                          __HIP_MEMORY_SCOPE_AGENT)
                   == (unsigned)(nb - 1)) ? 1u : 0u;
    __syncthreads();
    if (!is_last) return;

    __shared__ double    ssum[BINS];
    __shared__ long long scnt[BINS];
    for (int b = wave; b < BINS; b += 4) {   // 4 waves cover 10 bins
        double acc2 = 0.0; long long cc = 0;
        for (int i = lane; i < nb; i += 64) {
            float fv = __hip_atomic_load(&bsum[(long long)b * nb + i],
                                         __ATOMIC_RELAXED, __HIP_MEMORY_SCOPE_AGENT);
            int   iv = __hip_atomic_load(&bcnt[(long long)b * nb + i],
                                         __ATOMIC_RELAXED, __HIP_MEMORY_SCOPE_AGENT);
            acc2 += (double)fv;
            cc   += (long long)iv;
        }
        for (int off = 32; off; off >>= 1) {
            acc2 += __shfl_down(acc2, off);
            cc   += __shfl_down(cc, off);
        }
        if (lane == 0) { ssum[b] = acc2; scnt[b] = cc; }
    }
    __syncthreads();
    if (tid == 0) {
        int nn = 0;
#pragma unroll
        for (int b = 0; b < BINS; ++b) nn += (scnt[b] > 0) ? 1 : 0;
        double loss = 0.0;
        if (nn > 0) {
#pragma unroll
            for (int b = 0; b < BINS; ++b)
                if (scnt[b] > 0)
                    loss += ssum[b] / ((double)scnt[b] * (double)nn);
        }
        out[0] = (float)loss;
    }
}

extern "C" void kernel_launch(void* const* d_in, const int* in_sizes, int n_in,
                              void* d_out, int out_size, void* d_ws, size_t ws_size,
                              hipStream_t stream) {
    const float* pred = (const float*)d_in[0];
    const float* tgt  = (const float*)d_in[1];
    float* out = (float*)d_out;
    const long long n = (long long)in_sizes[0];

    int nb = 2048;
    const size_t per_block = (size_t)BINS * (sizeof(float) + sizeof(int)); // 80 B
    while (nb > 1 && (size_t)nb * per_block + sizeof(unsigned int) > ws_size)
        nb >>= 1;

    float*        bsum = (float*)d_ws;
    int*          bcnt = (int*)(bsum + (size_t)BINS * nb);
    unsigned int* done = (unsigned int*)(bcnt + (size_t)BINS * nb);

    // zero the ticket every call (captured into the graph -> every replay)
    hipMemsetAsync(done, 0, sizeof(unsigned int), stream);
    ghm_fused<<<nb, 256, 0, stream>>>(pred, tgt, n, nb, bsum, bcnt, done, out);
}